// Round 10
// baseline (389.721 us; speedup 1.0000x reference)
//
#include <hip/hip_runtime.h>
#include <hip/hip_bf16.h>

#define H 32
#define DOUT 16
#define NPITCH 72    // ushorts per node A row (144 B) in node_mfma staging
#define PADC 96      // padded slots per row (deg~Poisson(32), P(>96)~4e-20)
#define RECU 64      // ushorts per node record: [h bf16 x32 | x f32 x16] = 128 B
#define RECF 32      // floats per node record
#define EGRID 4096   // edge kernel blocks (grid-stride, 16/CU)

typedef unsigned short ushort_t;
typedef __attribute__((ext_vector_type(8))) short bf16x8;
typedef __attribute__((ext_vector_type(4))) float f32x4;
typedef __attribute__((ext_vector_type(4))) unsigned int u32x4;

__device__ __forceinline__ float silu(float v) {
    return v * __builtin_amdgcn_rcpf(1.0f + __expf(-v));
}
__device__ __forceinline__ ushort_t f2bf(float f) {
    unsigned int u = __float_as_uint(f);
    unsigned int r = (u + 0x7FFFu + ((u >> 16) & 1u)) >> 16;  // RNE
    return (ushort_t)r;
}
__device__ __forceinline__ unsigned pk2bf(float a, float b) {  // packed RNE pair
    __hip_bfloat162 h = __float22bfloat162_rn(make_float2(a, b));
    return *reinterpret_cast<unsigned*>(&h);
}
__device__ __forceinline__ bf16x8 bfcat(unsigned a, unsigned b, unsigned c, unsigned d) {
    union { u32x4 u; bf16x8 v; } x;
    x.u = (u32x4){a, b, c, d};
    return x.v;
}
// DPP move (old=0, all rows/banks, bound_ctrl): pure-VALU lane permute
template<int C>
__device__ __forceinline__ float dmov(float x) {
    return __int_as_float(__builtin_amdgcn_update_dpp(0, __float_as_int(x), C, 0xF, 0xF, true));
}
// full sum over each 16-lane group, 4 v_add_f32_dpp (no LDS pipe)
__device__ __forceinline__ float red16(float v) {
    v += dmov<0xB1>(v);
    v += dmov<0x4E>(v);
    v += dmov<0x141>(v);
    v += dmov<0x140>(v);
    return v;
}
// sum over the 4 lanes {i, i^16, i^32, i^48} (same nidx across q-groups)
__device__ __forceinline__ float sumq(float v) {
    v += __shfl_xor(v, 32, 64);
    v += __int_as_float(__builtin_amdgcn_ds_swizzle(__float_as_int(v), 0x401F)); // xor16
    return v;
}

// ---- fused prologue: init (record/pos4/h0/weight-pack) + CSR-pad scatter ----
// The two halves touch DISJOINT outputs (rec/h/pos4/weights vs deg/pad) so
// they run as one kernel on different block ranges and overlap on the machine.
// deg must be zeroed by the preceding memset (scatter blocks may run first).
// Scatter is SINGLE-PASS: each edge is read exactly once (no XCD slice
// replay); atomic append gives a unique slot regardless of writer XCD.
// Weight packing (as before):
//   kperm(g, j) = (j<4) ? 4g+j : 16+4g+(j-4), g = lane>>4  (W2B/CW1B)
//   W1B kc==2 K-tail replicates the radial col at k=0,8,16,24 (partial radials
//   summed by the MFMA); k==4 carries the baked eb1 bias (pairs with 1.0).
__global__ __launch_bounds__(256) void prologue(
    const float* __restrict__ node_attrs, const float* __restrict__ positions,
    const float* __restrict__ projW, const float* __restrict__ embW,
    const float* __restrict__ embB,
    const float* __restrict__ eW1, const float* __restrict__ eb1,
    const float* __restrict__ eW2, const float* __restrict__ cW1,
    const float* __restrict__ nW1, const float* __restrict__ nW2,
    float* __restrict__ recf, ushort_t* __restrict__ rech,
    float* __restrict__ h, float* __restrict__ pos4, int* __restrict__ deg,
    ushort_t* __restrict__ W1B, ushort_t* __restrict__ W2B,
    ushort_t* __restrict__ CW1B, ushort_t* __restrict__ NW1B,
    ushort_t* __restrict__ NW2B, int N,
    const int* __restrict__ row, const int* __restrict__ col,
    ushort_t* __restrict__ pad, int E, int ipBlocks)
{
    if ((int)blockIdx.x >= ipBlocks) {   // ---- scatter half (single-pass) ----
        int e = (blockIdx.x - ipBlocks) * 256 + threadIdx.x;
        if (e >= E) return;
        int r = row[e];
        int p = atomicAdd(&deg[r], 1);
        if (p < PADC) pad[(size_t)r * PADC + p] = (ushort_t)col[e];
        return;
    }
    // ---- init half ----
    int g = blockIdx.x * blockDim.x + threadIdx.x;
    if (g < N) {
        int n = g;
        float p0 = positions[3*n+0], p1 = positions[3*n+1], p2 = positions[3*n+2];
        pos4[4*n+0] = p0; pos4[4*n+1] = p1; pos4[4*n+2] = p2; pos4[4*n+3] = 0.0f;
        #pragma unroll
        for (int i = 0; i < DOUT; ++i)
            recf[(size_t)n*RECF + 16 + i] =
                projW[i*3+0]*p0 + projW[i*3+1]*p1 + projW[i*3+2]*p2;
        float a0 = node_attrs[3*n+0], a1 = node_attrs[3*n+1], a2 = node_attrs[3*n+2];
        #pragma unroll
        for (int j = 0; j < H; ++j) {
            float v = embB[j] + embW[j*3+0]*a0 + embW[j*3+1]*a1 + embW[j*3+2]*a2;
            h[(size_t)n*H+j] = v;
            rech[(size_t)n*RECU + j] = f2bf(v);
        }
        return;
    }
    int t = g - N;
    if (t < 6144) {  // edge W1: kc0/kc1 = h cols; kc2 = K-tail (see header)
        int j = t & 7; int r1 = t >> 3;
        int lane = r1 & 63; int r2 = r1 >> 6;
        int nt = r2 & 1; int r3 = r2 >> 1;
        int kc = r3 % 3; int l = r3 / 3;
        int n = 16 * nt + (lane & 15);
        int kk = 8 * (lane >> 4) + j;
        float v = 0.0f;
        if (kc < 2) {
            v = eW1[(l * 32 + n) * 68 + 32 * kc + kk];
        } else {
            if ((kk & 7) == 0) v = eW1[(l * 32 + n) * 68 + 64];       // radial col x4
            else if (kk <= 3)  v = eW1[(l * 32 + n) * 68 + 64 + kk];  // ea cols
            else if (kk == 4)  v = eb1[l * 32 + n];                   // baked bias
        }
        W1B[t] = f2bf(v);
    }
    if (t < 4096) {  // node W1: K=64
        int j = t & 7; int lane = (t >> 3) & 63;
        int nt = (t >> 9) & 1; int kc = (t >> 10) & 1; int l = (t >> 11) & 1;
        int n = 16 * nt + (lane & 15);
        int k = 32 * kc + 8 * (lane >> 4) + j;
        NW1B[t] = f2bf(nW1[(l * 32 + n) * 64 + k]);
    }
    if (t < 2048) {  // edge W2 / coord W1 (k-permuted) / node W2: K=32
        int j = t & 7; int lane = (t >> 3) & 63;
        int nt = (t >> 9) & 1; int l = t >> 10;
        int n = 16 * nt + (lane & 15);
        int gq = lane >> 4;
        int k  = 8 * gq + j;
        int kp = (j < 4) ? (4 * gq + j) : (16 + 4 * gq + (j - 4));
        W2B[t]  = f2bf(eW2[(l * 32 + n) * 32 + kp]);
        CW1B[t] = f2bf(cW1[(l * 32 + n) * 32 + kp]);
        NW2B[t] = f2bf(nW2[(l * 32 + n) * 32 + k]);
    }
}

// ---- node-centric MFMA edge kernel, weights-in-LDS (R8, unchanged) ----------
// Single compute chain, VGPR-lean, TLP over ILP. Grid-stride waves; one node
// per wave at a time, ceil(deg/16) 16-edge MFMA tiles from pad. Per-edge
// gathers hit ONE 128B record line + one pos4 line. Weight frags re-read from
// LDS per tile (opaque offset defeats LICM). 2-deep neighbor-index pipeline.
// Radial via per-lane PARTIALS into replicated K-slots. Register aggregation +
// DPP butterfly, plain stores, no atomics.
// LAST=1: m-agg dead; fuse pred = lin*x_new.
template<int LAST>
__global__ __launch_bounds__(256, 4) void edge_mfma(
    const ushort_t* __restrict__ pad, const int* __restrict__ deg,
    const float* __restrict__ pos4,
    const ushort_t* __restrict__ rec_in,
    const ushort_t* __restrict__ W1B, const ushort_t* __restrict__ W2B,
    const ushort_t* __restrict__ CW1B,
    const float* __restrict__ eb2, const float* __restrict__ cb1,
    const float* __restrict__ cw2,
    float* __restrict__ rec_out, ushort_t* __restrict__ maggb,
    const float* __restrict__ lin, float* __restrict__ outp, int N)
{
    __shared__ __align__(16) ushort_t WL[5120];   // [w1 6KB | w2 2KB | cw 2KB]

    const int tid = threadIdx.x;
    const int lane = tid & 63;
    const int w = tid >> 6;
    const int nidx = lane & 15;
    const int q = lane >> 4;
    const float* recf = (const float*)rec_in;

    {   // stage weight tables (640 x uint4 = 10 KB)
        uint4* d = (uint4*)WL;
        const uint4* s1 = (const uint4*)W1B;
        for (int i = tid; i < 384; i += 256) d[i] = s1[i];
        const uint4* s2 = (const uint4*)W2B;
        const uint4* s3 = (const uint4*)CW1B;
        for (int i = tid; i < 128; i += 256) { d[384+i] = s2[i]; d[512+i] = s3[i]; }
    }
    __syncthreads();
    const char* WB = (const char*)WL;
    // row-term fragments: truly loop-invariant, keep in registers (8 VGPRs)
    const bf16x8 w1r0 = *(const bf16x8*)(WB + 0    + lane*16);
    const bf16x8 w1r1 = *(const bf16x8*)(WB + 1024 + lane*16);
    unsigned wb = (unsigned)(lane * 16);   // opaque per-tile frag offset

    // biases / cw2 for this lane's own dims {4q+r, 16+4q+r}
    const float4 eb2v0 = *(const float4*)(eb2 + 4*q);
    const float4 eb2v1 = *(const float4*)(eb2 + 16 + 4*q);
    const float4 cb1v0 = *(const float4*)(cb1 + 4*q);
    const float4 cb1v1 = *(const float4*)(cb1 + 16 + 4*q);
    const float4 cw2v0 = *(const float4*)(cw2 + 4*q);
    const float4 cw2v1 = *(const float4*)(cw2 + 16 + 4*q);
    float4 l0, l1, l2;
    if (LAST) {
        l0 = *(const float4*)(lin + 0*DOUT + 4*q);
        l1 = *(const float4*)(lin + 1*DOUT + 4*q);
        l2 = *(const float4*)(lin + 2*DOUT + 4*q);
    }
    const bool q0 = (q == 0);

    const f32x4 z4 = {0.0f, 0.0f, 0.0f, 0.0f};
    const int wv = blockIdx.x * 4 + w;
    const int nwv = gridDim.x * 4;

    #pragma unroll 1
    for (int nid = wv; nid < N; nid += nwv) {
        const int dgf = deg[nid];
        const int dg  = min(dgf, PADC);
        const int T   = (dg + 15) >> 4;
        const ushort_t* prow = pad + (size_t)nid * PADC;

        // per-node state (one record line + pos4)
        bf16x8 hR = *(const bf16x8*)(rec_in + (size_t)nid * RECU + 8*q);
        float4 xa = *(const float4*)(recf + (size_t)nid * RECF + 16 + 4*q);
        float4 pr = *(const float4*)(pos4 + (size_t)nid * 4);
        // row-term of MLP1: identical for every tile -> acc init
        f32x4 n0 = __builtin_amdgcn_mfma_f32_16x16x32_bf16(w1r0, hR, z4, 0, 0, 0);
        f32x4 n1 = __builtin_amdgcn_mfma_f32_16x16x32_bf16(w1r1, hR, z4, 0, 0, 0);

        float accm0 = 0, accm1 = 0, accm2 = 0, accm3 = 0;
        float accm4 = 0, accm5 = 0, accm6 = 0, accm7 = 0;
        float accx0 = 0, accx1 = 0, accx2 = 0, accx3 = 0;

        // prefetch tile 0 gathers
        bool veC = (nidx < dg);
        int  cC  = veC ? (int)prow[nidx] : nid;
        bf16x8 hCC = *(const bf16x8*)(rec_in + (size_t)cC * RECU + 8*q);
        float4 xbC = *(const float4*)(recf + (size_t)cC * RECF + 16 + 4*q);
        float4 pc  = *(const float4*)(pos4 + (size_t)cC * 4);
        // neighbor index for tile 1, loaded one level ahead of its gathers
        int idxN = (16 + nidx < dg) ? (int)prow[16 + nidx] : -1;

        #pragma unroll 1
        for (int t = 0; t < T; ++t) {
            asm volatile("" : "+v"(wb));   // defeat LICM on LDS frag reads
            // gathers for tile t+1: index already in-register
            bool veN = idxN >= 0;
            int  cN  = veN ? idxN : nid;
            bf16x8 hCN = *(const bf16x8*)(rec_in + (size_t)cN * RECU + 8*q);
            float4 xbN = *(const float4*)(recf + (size_t)cN * RECF + 16 + 4*q);
            float4 pn  = *(const float4*)(pos4 + (size_t)cN * 4);
            // index for tile t+2 (2-deep, off the critical chain)
            int ei2 = (t + 2) * 16 + nidx;
            idxN = (ei2 < dg) ? (int)prow[ei2] : -1;

            // current tile compute
            float dd0 = xa.x - xbC.x, dd1 = xa.y - xbC.y;
            float dd2 = xa.z - xbC.z, dd3 = xa.w - xbC.w;
            float rp = dd0*dd0 + dd1*dd1 + dd2*dd2 + dd3*dd3;  // PARTIAL radial
            float ea0 = pr.x - pc.x, ea1 = pr.y - pc.y, ea2 = pr.z - pc.z;
            unsigned k2w0 = pk2bf(rp, q0 ? ea0 : 0.0f);
            unsigned k2w1 = q0 ? pk2bf(ea1, ea2) : 0u;
            bf16x8 bK2 = bfcat(k2w0, k2w1, q0 ? 0x3F80u : 0u, 0u);

            // MLP1 remainder: col-term + K-tail on top of row-term init
            bf16x8 wc0 = *(const bf16x8*)(WB + 2048 + wb);
            bf16x8 wc1 = *(const bf16x8*)(WB + 3072 + wb);
            bf16x8 wt0 = *(const bf16x8*)(WB + 4096 + wb);
            bf16x8 wt1 = *(const bf16x8*)(WB + 5120 + wb);
            f32x4 a0 = n0, a1 = n1;
            a0 = __builtin_amdgcn_mfma_f32_16x16x32_bf16(wc0, hCC, a0, 0, 0, 0);
            a1 = __builtin_amdgcn_mfma_f32_16x16x32_bf16(wc1, hCC, a1, 0, 0, 0);
            a0 = __builtin_amdgcn_mfma_f32_16x16x32_bf16(wt0, bK2, a0, 0, 0, 0);
            a1 = __builtin_amdgcn_mfma_f32_16x16x32_bf16(wt1, bK2, a1, 0, 0, 0);

            bf16x8 bm1 = bfcat(pk2bf(silu(a0[0]), silu(a0[1])),
                               pk2bf(silu(a0[2]), silu(a0[3])),
                               pk2bf(silu(a1[0]), silu(a1[1])),
                               pk2bf(silu(a1[2]), silu(a1[3])));

            bf16x8 w20 = *(const bf16x8*)(WB + 6144 + wb);
            bf16x8 w21 = *(const bf16x8*)(WB + 7168 + wb);
            f32x4 b0 = __builtin_amdgcn_mfma_f32_16x16x32_bf16(w20, bm1, z4, 0, 0, 0);
            f32x4 b1 = __builtin_amdgcn_mfma_f32_16x16x32_bf16(w21, bm1, z4, 0, 0, 0);

            float sv0 = silu(b0[0] + eb2v0.x), sv1 = silu(b0[1] + eb2v0.y);
            float sv2 = silu(b0[2] + eb2v0.z), sv3 = silu(b0[3] + eb2v0.w);
            float sv4 = silu(b1[0] + eb2v1.x), sv5 = silu(b1[1] + eb2v1.y);
            float sv6 = silu(b1[2] + eb2v1.z), sv7 = silu(b1[3] + eb2v1.w);

            bf16x8 bm2 = bfcat(pk2bf(sv0, sv1), pk2bf(sv2, sv3),
                               pk2bf(sv4, sv5), pk2bf(sv6, sv7));

            bf16x8 cw0 = *(const bf16x8*)(WB + 8192 + wb);
            bf16x8 cw1 = *(const bf16x8*)(WB + 9216 + wb);
            f32x4 c0 = __builtin_amdgcn_mfma_f32_16x16x32_bf16(cw0, bm2, z4, 0, 0, 0);
            f32x4 c1 = __builtin_amdgcn_mfma_f32_16x16x32_bf16(cw1, bm2, z4, 0, 0, 0);
            float pp = silu(c0[0] + cb1v0.x) * cw2v0.x + silu(c0[1] + cb1v0.y) * cw2v0.y
                     + silu(c0[2] + cb1v0.z) * cw2v0.z + silu(c0[3] + cb1v0.w) * cw2v0.w
                     + silu(c1[0] + cb1v1.x) * cw2v1.x + silu(c1[1] + cb1v1.y) * cw2v1.y
                     + silu(c1[2] + cb1v1.z) * cw2v1.z + silu(c1[3] + cb1v1.w) * cw2v1.w;
            pp = sumq(pp);                  // cm at all lanes (off inter-tile path)

            if (!LAST) {                    // m-agg dead on last layer
                float msk = veC ? 1.0f : 0.0f;
                accm0 = fmaf(sv0, msk, accm0); accm1 = fmaf(sv1, msk, accm1);
                accm2 = fmaf(sv2, msk, accm2); accm3 = fmaf(sv3, msk, accm3);
                accm4 = fmaf(sv4, msk, accm4); accm5 = fmaf(sv5, msk, accm5);
                accm6 = fmaf(sv6, msk, accm6); accm7 = fmaf(sv7, msk, accm7);
            }
            // padded lanes have cC==nid -> dd==0 -> no mask needed
            accx0 += dd0 * pp; accx1 += dd1 * pp;
            accx2 += dd2 * pp; accx3 += dd3 * pp;

            veC = veN; cC = cN; hCC = hCN; xbC = xbN; pc = pn;
        }

        // DPP butterfly over the node's 16 edge lanes (pure VALU)
        accx0 = red16(accx0); accx1 = red16(accx1);
        accx2 = red16(accx2); accx3 = red16(accx3);
        if (!LAST) {
            accm0 = red16(accm0); accm1 = red16(accm1);
            accm2 = red16(accm2); accm3 = red16(accm3);
            accm4 = red16(accm4); accm5 = red16(accm5);
            accm6 = red16(accm6); accm7 = red16(accm7);
        }

        const float inv = __builtin_amdgcn_rcpf(fmaxf((float)dgf, 1.0f));
        const float xn0 = xa.x + accx0 * inv;
        const float xn1 = xa.y + accx1 * inv;
        const float xn2 = xa.z + accx2 * inv;
        const float xn3 = xa.w + accx3 * inv;

        if (!LAST) {
            if (nidx == 0) {
                *(float4*)(rec_out + (size_t)nid * RECF + 16 + 4*q) =
                    make_float4(xn0, xn1, xn2, xn3);
                *(uint2*)(maggb + (size_t)nid * H + 4*q) =
                    make_uint2(pk2bf(accm0, accm1), pk2bf(accm2, accm3));
                *(uint2*)(maggb + (size_t)nid * H + 16 + 4*q) =
                    make_uint2(pk2bf(accm4, accm5), pk2bf(accm6, accm7));
            }
        } else {   // fuse pred = lin * x_new
            float p0 = xn0*l0.x + xn1*l0.y + xn2*l0.z + xn3*l0.w;
            float p1 = xn0*l1.x + xn1*l1.y + xn2*l1.z + xn3*l1.w;
            float p2 = xn0*l2.x + xn1*l2.y + xn2*l2.z + xn3*l2.w;
            p0 = sumq(p0); p1 = sumq(p1); p2 = sumq(p2);
            if (lane == 0) {
                outp[(size_t)nid*3+0] = p0;
                outp[(size_t)nid*3+1] = p1;
                outp[(size_t)nid*3+2] = p2;
            }
        }
    }
}

// ---- MFMA node kernel: h update only; DENSE h-writes via wave-local LDS ----
__global__ __launch_bounds__(256) void node_mfma(
    const float* __restrict__ h_in, const ushort_t* __restrict__ rec_in,
    const ushort_t* __restrict__ maggb,
    const ushort_t* __restrict__ W1B, const ushort_t* __restrict__ W2B,
    const float* __restrict__ b1g, const float* __restrict__ b2g,
    ushort_t* __restrict__ rec_out, int N)
{
    __shared__ __align__(16) ushort_t Nin[64 * NPITCH];

    const int tid = threadIdx.x;
    const int n0 = blockIdx.x * 64;
    const int lane = tid & 63;
    const int w = tid >> 6;
    const int nidx = lane & 15;
    const int q = lane >> 4;

    bf16x8 w1f[2][2], w2f[2];
    #pragma unroll
    for (int kc = 0; kc < 2; ++kc)
        #pragma unroll
        for (int nt = 0; nt < 2; ++nt)
            w1f[kc][nt] = *(const bf16x8*)(W1B + (size_t)((kc*2+nt)*64 + lane) * 8);
    #pragma unroll
    for (int nt = 0; nt < 2; ++nt)
        w2f[nt] = *(const bf16x8*)(W2B + (size_t)(nt*64 + lane) * 8);
    float b1v0 = b1g[nidx], b1v1 = b1g[16+nidx];
    float b2v0 = b2g[nidx], b2v1 = b2g[16+nidx];

    {   // stage nin = [h bf16 (from record) | magg bf16] (both pre-packed)
        int e = tid >> 2, part = tid & 3;
        int n = n0 + e;
        uint4 v0 = make_uint4(0,0,0,0), v1 = v0;
        if (n < N) {
            const uint4* hp = (part < 2)
                ? (const uint4*)(rec_in + (size_t)n * RECU + part * 16)
                : (const uint4*)(maggb  + (size_t)n * H + (part - 2) * 16);
            v0 = hp[0]; v1 = hp[1];
        }
        uint4* dst = (uint4*)((char*)Nin + e * 144 + part * 32);
        dst[0] = v0; dst[1] = v1;
    }
    __syncthreads();

    const int mrow = 16 * w + nidx;
    bf16x8 a0 = *(const bf16x8*)(Nin + mrow * NPITCH + 8 * q);
    bf16x8 a1 = *(const bf16x8*)(Nin + mrow * NPITCH + 32 + 8 * q);
    f32x4 z4 = {0.0f, 0.0f, 0.0f, 0.0f};
    f32x4 acc0 = z4, acc1 = z4;
    acc0 = __builtin_amdgcn_mfma_f32_16x16x32_bf16(a0, w1f[0][0], acc0, 0, 0, 0);
    acc0 = __builtin_amdgcn_mfma_f32_16x16x32_bf16(a1, w1f[1][0], acc0, 0, 0, 0);
    acc1 = __builtin_amdgcn_mfma_f32_16x16x32_bf16(a0, w1f[0][1], acc1, 0, 0, 0);
    acc1 = __builtin_amdgcn_mfma_f32_16x16x32_bf16(a1, w1f[1][1], acc1, 0, 0, 0);

    ushort_t* u1w = Nin + w * 16 * NPITCH;   // own slab reuse (wave-ordered LDS)
    #pragma unroll
    for (int r = 0; r < 4; ++r) {
        unsigned u = pk2bf(silu(acc0[r] + b1v0), silu(acc1[r] + b1v1));
        u1w[(4*q + r) * 40 + nidx]      = (ushort_t)(u & 0xFFFFu);
        u1w[(4*q + r) * 40 + 16 + nidx] = (ushort_t)(u >> 16);
    }
    bf16x8 au = *(const bf16x8*)(u1w + nidx * 40 + 8 * q);
    f32x4 d0 = __builtin_amdgcn_mfma_f32_16x16x32_bf16(au, w2f[0], z4, 0, 0, 0);
    f32x4 d1 = __builtin_amdgcn_mfma_f32_16x16x32_bf16(au, w2f[1], z4, 0, 0, 0);
    // transpose h-out through the same slab (au consumed; same-wave ordering),
    // then write each node's 64B h-block as dense uint4s.
    #pragma unroll
    for (int r = 0; r < 4; ++r) {
        int n = n0 + 16*w + 4*q + r;
        if (n < N) {
            size_t i0 = (size_t)n * H + nidx, i1 = i0 + 16;
            u1w[(4*q + r) * 40 + nidx]      = f2bf(h_in[i0] + d0[r] + b2v0);
            u1w[(4*q + r) * 40 + 16 + nidx] = f2bf(h_in[i1] + d1[r] + b2v1);
        }
    }
    {
        int el = lane >> 2, c = lane & 3;       // 16 rows x 4 chunks = 64 lanes
        int n = n0 + 16*w + el;
        if (n < N) {
            uint4 v = *(const uint4*)((const char*)u1w + el * 80 + c * 16);
            *(uint4*)((char*)rec_out + (size_t)n * 128 + c * 16) = v;
        }
    }
}

extern "C" void kernel_launch(void* const* d_in, const int* in_sizes, int n_in,
                              void* d_out, int out_size, void* d_ws, size_t ws_size,
                              hipStream_t stream) {
    const float* node_attrs = (const float*)d_in[0];
    const float* positions  = (const float*)d_in[1];
    const int*   edge_index = (const int*)d_in[2];
    const float* proj_W   = (const float*)d_in[3];
    const float* emb_in_W = (const float*)d_in[4];
    const float* emb_in_b = (const float*)d_in[5];
    const float* edge_W1  = (const float*)d_in[6];
    const float* edge_b1  = (const float*)d_in[7];
    const float* edge_W2  = (const float*)d_in[8];
    const float* edge_b2  = (const float*)d_in[9];
    const float* node_W1  = (const float*)d_in[10];
    const float* node_b1  = (const float*)d_in[11];
    const float* node_W2  = (const float*)d_in[12];
    const float* node_b2  = (const float*)d_in[13];
    const float* coord_W1 = (const float*)d_in[14];
    const float* coord_b1 = (const float*)d_in[15];
    const float* coord_W2 = (const float*)d_in[16];
    const float* lin_W    = (const float*)d_in[19];

    const int N = in_sizes[0] / 3;
    const int E = in_sizes[2] / 2;
    const int* row = edge_index;
    const int* col = edge_index + E;

    float* rec0f = (float*)d_ws;                       // 32N f32 (128B records)
    float* rec1f = rec0f + (size_t)RECF * N;           // 32N f32
    float* h0    = rec1f + (size_t)RECF * N;           // 32N f32 (residual)
    float* pos4  = h0 + (size_t)H * N;                 // 4N f32
    ushort_t* maggb = (ushort_t*)(pos4 + (size_t)4 * N); // 32N us (bf16 m-agg)
    ushort_t* W1B  = maggb + (size_t)H * N;            // 6144
    ushort_t* W2B  = W1B + 6144;                       // 2048
    ushort_t* CW1B = W2B + 2048;                       // 2048
    ushort_t* NW1B = CW1B + 2048;                      // 4096
    ushort_t* NW2B = NW1B + 4096;                      // 2048
    int* deg    = (int*)(NW2B + 2048);                 // N
    ushort_t* pad  = (ushort_t*)(deg + N);             // N*PADC ushorts

    int eB256 = (E + 255) / 256;
    int nTiles = (N + 63) / 64;
    int ipBlocks = (N + 6144 + 255) / 256;

    hipMemsetAsync(deg, 0, (size_t)N * sizeof(int), stream);

    // fused prologue: init blocks [0, ipBlocks) + single-pass scatter after
    prologue<<<ipBlocks + eB256, 256, 0, stream>>>(
        node_attrs, positions, proj_W, emb_in_W, emb_in_b,
        edge_W1, edge_b1, edge_W2, coord_W1, node_W1, node_W2,
        rec0f, (ushort_t*)rec0f, h0, pos4, deg, W1B, W2B, CW1B, NW1B, NW2B, N,
        row, col, pad, E, ipBlocks);

    // layer 0: edge (magg + x into rec1) then node h update (into rec1)
    edge_mfma<0><<<EGRID, 256, 0, stream>>>(
        pad, deg, pos4, (ushort_t*)rec0f,
        W1B, W2B, CW1B, edge_b2, coord_b1, coord_W2,
        rec1f, maggb, nullptr, nullptr, N);
    node_mfma<<<nTiles, 256, 0, stream>>>(
        h0, (ushort_t*)rec0f, maggb, NW1B, NW2B, node_b1, node_b2,
        (ushort_t*)rec1f, N);
    // layer 1: edge with fused lin projection (final h, x, magg all dead)
    edge_mfma<1><<<EGRID, 256, 0, stream>>>(
        pad, deg, pos4, (ushort_t*)rec1f,
        W1B + 3072, W2B + 1024, CW1B + 1024,
        edge_b2 + H, coord_b1 + H, coord_W2 + H,
        nullptr, nullptr, lin_W, (float*)d_out, N);
}

// Round 11
// 343.581 us; speedup vs baseline: 1.1343x; 1.1343x over previous
//
#include <hip/hip_runtime.h>
#include <hip/hip_bf16.h>

#define H 32
#define DOUT 16
#define NPITCH 72    // ushorts per node A row (144 B) in node_mfma staging
#define PADC 96      // padded slots per row (deg~Poisson(32), P(>96)~4e-20)
#define NSLICE 8     // row slices, mapped to XCDs via blockIdx & 7
#define RECU 64      // ushorts per node record: [h bf16 x32 | x f32 x16] = 128 B
#define RECF 32      // floats per node record
#define EGRID 2048   // edge kernel blocks (grid-stride, 8/CU)

typedef unsigned short ushort_t;
typedef __attribute__((ext_vector_type(8))) short bf16x8;
typedef __attribute__((ext_vector_type(4))) float f32x4;
typedef __attribute__((ext_vector_type(4))) unsigned int u32x4;

__device__ __forceinline__ float silu(float v) {
    return v * __builtin_amdgcn_rcpf(1.0f + __expf(-v));
}
__device__ __forceinline__ ushort_t f2bf(float f) {
    unsigned int u = __float_as_uint(f);
    unsigned int r = (u + 0x7FFFu + ((u >> 16) & 1u)) >> 16;  // RNE
    return (ushort_t)r;
}
__device__ __forceinline__ unsigned pk2bf(float a, float b) {  // packed RNE pair
    __hip_bfloat162 h = __float22bfloat162_rn(make_float2(a, b));
    return *reinterpret_cast<unsigned*>(&h);
}
__device__ __forceinline__ bf16x8 bfcat(unsigned a, unsigned b, unsigned c, unsigned d) {
    union { u32x4 u; bf16x8 v; } x;
    x.u = (u32x4){a, b, c, d};
    return x.v;
}
// DPP move (old=0, all rows/banks, bound_ctrl): pure-VALU lane permute
template<int C>
__device__ __forceinline__ float dmov(float x) {
    return __int_as_float(__builtin_amdgcn_update_dpp(0, __float_as_int(x), C, 0xF, 0xF, true));
}
// full sum over each 16-lane group, 4 v_add_f32_dpp (no LDS pipe)
__device__ __forceinline__ float red16(float v) {
    v += dmov<0xB1>(v);
    v += dmov<0x4E>(v);
    v += dmov<0x141>(v);
    v += dmov<0x140>(v);
    return v;
}
// sum over the 4 lanes {i, i^16, i^32, i^48} (same nidx across q-groups)
__device__ __forceinline__ float sumq(float v) {
    v += __shfl_xor(v, 32, 64);
    v += __int_as_float(__builtin_amdgcn_ds_swizzle(__float_as_int(v), 0x401F)); // xor16
    return v;
}

// ---- fused prologue: coalesced init + XCD-SLICED CSR-pad scatter ------------
// Init half: 8 threads per node; every store instruction is lane-consecutive
// (float4/uint2), replacing the old 48 scalar 128B-strided stores per node.
// Scatter half: R9's XCD row-slice replay (blockIdx&7 -> slice). Slicing is
// MANDATORY: R10 measured 110 MB writeback (9.6x amplification) without it --
// per-XCD L2s partially dirty shared pad lines. Atomics were not the cost.
// Weight packing (unchanged):
//   kperm(g, j) = (j<4) ? 4g+j : 16+4g+(j-4), g = lane>>4  (W2B/CW1B)
//   W1B kc==2 K-tail replicates the radial col at k=0,8,16,24; k==4 = eb1.
__global__ __launch_bounds__(256) void prologue(
    const float* __restrict__ node_attrs, const float* __restrict__ positions,
    const float* __restrict__ projW, const float* __restrict__ embW,
    const float* __restrict__ embB,
    const float* __restrict__ eW1, const float* __restrict__ eb1,
    const float* __restrict__ eW2, const float* __restrict__ cW1,
    const float* __restrict__ nW1, const float* __restrict__ nW2,
    float* __restrict__ recf, ushort_t* __restrict__ rech,
    float* __restrict__ h, float* __restrict__ pos4, int* __restrict__ deg,
    ushort_t* __restrict__ W1B, ushort_t* __restrict__ W2B,
    ushort_t* __restrict__ CW1B, ushort_t* __restrict__ NW1B,
    ushort_t* __restrict__ NW2B, int N,
    const int* __restrict__ row, const int* __restrict__ col,
    ushort_t* __restrict__ pad, int E, int rstep, int ipBlocks)
{
    if ((int)blockIdx.x >= ipBlocks) {   // ---- scatter half (XCD-sliced) ----
        int b = blockIdx.x - ipBlocks;
        int slice = b & (NSLICE - 1);
        int e = (b >> 3) * 256 + threadIdx.x;
        if (e >= E) return;
        int r = row[e];
        int rlo = slice * rstep;
        if ((unsigned)(r - rlo) >= (unsigned)rstep) return;
        int p = atomicAdd(&deg[r], 1);
        if (p < PADC) pad[(size_t)r * PADC + p] = (ushort_t)col[e];
        return;
    }
    // ---- init half: 8 threads per node, coalesced vector stores ----
    int g = blockIdx.x * blockDim.x + threadIdx.x;
    int n = g >> 3, c = g & 7;
    if (n < N) {
        float p0 = positions[3*n+0], p1 = positions[3*n+1], p2 = positions[3*n+2];
        float a0 = node_attrs[3*n+0], a1 = node_attrs[3*n+1], a2 = node_attrs[3*n+2];
        // h dims 4c..4c+3 (f32 + bf16 mirror), lane-consecutive stores
        float hv[4];
        #pragma unroll
        for (int i = 0; i < 4; ++i) {
            int j = 4*c + i;
            hv[i] = embB[j] + embW[j*3+0]*a0 + embW[j*3+1]*a1 + embW[j*3+2]*a2;
        }
        *(float4*)(h + (size_t)n*H + 4*c) = make_float4(hv[0], hv[1], hv[2], hv[3]);
        *(uint2*)(rech + (size_t)n*RECU + 4*c) =
            make_uint2(pk2bf(hv[0], hv[1]), pk2bf(hv[2], hv[3]));
        if (c < 4) {        // x dims 4c..4c+3
            float xv[4];
            #pragma unroll
            for (int i = 0; i < 4; ++i) {
                int d = 4*c + i;
                xv[i] = projW[d*3+0]*p0 + projW[d*3+1]*p1 + projW[d*3+2]*p2;
            }
            *(float4*)(recf + (size_t)n*RECF + 16 + 4*c) =
                make_float4(xv[0], xv[1], xv[2], xv[3]);
        } else if (c == 4) {
            *(float4*)(pos4 + (size_t)n*4) = make_float4(p0, p1, p2, 0.0f);
        }
        return;
    }
    int t = g - 8*N;
    if (t < 0) return;
    if (t < 6144) {  // edge W1: kc0/kc1 = h cols; kc2 = K-tail (see header)
        int j = t & 7; int r1 = t >> 3;
        int lane = r1 & 63; int r2 = r1 >> 6;
        int nt = r2 & 1; int r3 = r2 >> 1;
        int nn = 16 * nt + (lane & 15);
        int kc = r3 % 3; int l = r3 / 3;
        int kk = 8 * (lane >> 4) + j;
        float v = 0.0f;
        if (kc < 2) {
            v = eW1[(l * 32 + nn) * 68 + 32 * kc + kk];
        } else {
            if ((kk & 7) == 0) v = eW1[(l * 32 + nn) * 68 + 64];       // radial col x4
            else if (kk <= 3)  v = eW1[(l * 32 + nn) * 68 + 64 + kk];  // ea cols
            else if (kk == 4)  v = eb1[l * 32 + nn];                   // baked bias
        }
        W1B[t] = f2bf(v);
    }
    if (t < 4096) {  // node W1: K=64
        int j = t & 7; int lane = (t >> 3) & 63;
        int nt = (t >> 9) & 1; int kc = (t >> 10) & 1; int l = (t >> 11) & 1;
        int nn = 16 * nt + (lane & 15);
        int k = 32 * kc + 8 * (lane >> 4) + j;
        NW1B[t] = f2bf(nW1[(l * 32 + nn) * 64 + k]);
    }
    if (t < 2048) {  // edge W2 / coord W1 (k-permuted) / node W2: K=32
        int j = t & 7; int lane = (t >> 3) & 63;
        int nt = (t >> 9) & 1; int l = t >> 10;
        int nn = 16 * nt + (lane & 15);
        int gq = lane >> 4;
        int k  = 8 * gq + j;
        int kp = (j < 4) ? (4 * gq + j) : (16 + 4 * gq + (j - 4));
        W2B[t]  = f2bf(eW2[(l * 32 + nn) * 32 + kp]);
        CW1B[t] = f2bf(cW1[(l * 32 + nn) * 32 + kp]);
        NW2B[t] = f2bf(nW2[(l * 32 + nn) * 32 + k]);
    }
}

// ---- node-centric MFMA edge kernel, weights-in-LDS (R8/R9, unchanged) -------
// Single compute chain, VGPR-lean, TLP over ILP. Grid-stride waves; one node
// per wave at a time, ceil(deg/16) 16-edge MFMA tiles from pad. Per-edge
// gathers hit ONE 128B record line + one pos4 line. Weight frags re-read from
// LDS per tile (opaque offset defeats LICM). 2-deep neighbor-index pipeline.
// Radial via per-lane PARTIALS into replicated K-slots. Register aggregation +
// DPP butterfly, plain stores, no atomics.
// LAST=1: m-agg dead; fuse pred = lin*x_new.
template<int LAST>
__global__ __launch_bounds__(256, 4) void edge_mfma(
    const ushort_t* __restrict__ pad, const int* __restrict__ deg,
    const float* __restrict__ pos4,
    const ushort_t* __restrict__ rec_in,
    const ushort_t* __restrict__ W1B, const ushort_t* __restrict__ W2B,
    const ushort_t* __restrict__ CW1B,
    const float* __restrict__ eb2, const float* __restrict__ cb1,
    const float* __restrict__ cw2,
    float* __restrict__ rec_out, ushort_t* __restrict__ maggb,
    const float* __restrict__ lin, float* __restrict__ outp, int N)
{
    __shared__ __align__(16) ushort_t WL[5120];   // [w1 6KB | w2 2KB | cw 2KB]

    const int tid = threadIdx.x;
    const int lane = tid & 63;
    const int w = tid >> 6;
    const int nidx = lane & 15;
    const int q = lane >> 4;
    const float* recf = (const float*)rec_in;

    {   // stage weight tables (640 x uint4 = 10 KB)
        uint4* d = (uint4*)WL;
        const uint4* s1 = (const uint4*)W1B;
        for (int i = tid; i < 384; i += 256) d[i] = s1[i];
        const uint4* s2 = (const uint4*)W2B;
        const uint4* s3 = (const uint4*)CW1B;
        for (int i = tid; i < 128; i += 256) { d[384+i] = s2[i]; d[512+i] = s3[i]; }
    }
    __syncthreads();
    const char* WB = (const char*)WL;
    // row-term fragments: truly loop-invariant, keep in registers (8 VGPRs)
    const bf16x8 w1r0 = *(const bf16x8*)(WB + 0    + lane*16);
    const bf16x8 w1r1 = *(const bf16x8*)(WB + 1024 + lane*16);
    unsigned wb = (unsigned)(lane * 16);   // opaque per-tile frag offset

    // biases / cw2 for this lane's own dims {4q+r, 16+4q+r}
    const float4 eb2v0 = *(const float4*)(eb2 + 4*q);
    const float4 eb2v1 = *(const float4*)(eb2 + 16 + 4*q);
    const float4 cb1v0 = *(const float4*)(cb1 + 4*q);
    const float4 cb1v1 = *(const float4*)(cb1 + 16 + 4*q);
    const float4 cw2v0 = *(const float4*)(cw2 + 4*q);
    const float4 cw2v1 = *(const float4*)(cw2 + 16 + 4*q);
    float4 l0, l1, l2;
    if (LAST) {
        l0 = *(const float4*)(lin + 0*DOUT + 4*q);
        l1 = *(const float4*)(lin + 1*DOUT + 4*q);
        l2 = *(const float4*)(lin + 2*DOUT + 4*q);
    }
    const bool q0 = (q == 0);

    const f32x4 z4 = {0.0f, 0.0f, 0.0f, 0.0f};
    const int wv = blockIdx.x * 4 + w;
    const int nwv = gridDim.x * 4;

    #pragma unroll 1
    for (int nid = wv; nid < N; nid += nwv) {
        const int dgf = deg[nid];
        const int dg  = min(dgf, PADC);
        const int T   = (dg + 15) >> 4;
        const ushort_t* prow = pad + (size_t)nid * PADC;

        // per-node state (one record line + pos4)
        bf16x8 hR = *(const bf16x8*)(rec_in + (size_t)nid * RECU + 8*q);
        float4 xa = *(const float4*)(recf + (size_t)nid * RECF + 16 + 4*q);
        float4 pr = *(const float4*)(pos4 + (size_t)nid * 4);
        // row-term of MLP1: identical for every tile -> acc init
        f32x4 n0 = __builtin_amdgcn_mfma_f32_16x16x32_bf16(w1r0, hR, z4, 0, 0, 0);
        f32x4 n1 = __builtin_amdgcn_mfma_f32_16x16x32_bf16(w1r1, hR, z4, 0, 0, 0);

        float accm0 = 0, accm1 = 0, accm2 = 0, accm3 = 0;
        float accm4 = 0, accm5 = 0, accm6 = 0, accm7 = 0;
        float accx0 = 0, accx1 = 0, accx2 = 0, accx3 = 0;

        // prefetch tile 0 gathers
        bool veC = (nidx < dg);
        int  cC  = veC ? (int)prow[nidx] : nid;
        bf16x8 hCC = *(const bf16x8*)(rec_in + (size_t)cC * RECU + 8*q);
        float4 xbC = *(const float4*)(recf + (size_t)cC * RECF + 16 + 4*q);
        float4 pc  = *(const float4*)(pos4 + (size_t)cC * 4);
        // neighbor index for tile 1, loaded one level ahead of its gathers
        int idxN = (16 + nidx < dg) ? (int)prow[16 + nidx] : -1;

        #pragma unroll 1
        for (int t = 0; t < T; ++t) {
            asm volatile("" : "+v"(wb));   // defeat LICM on LDS frag reads
            // gathers for tile t+1: index already in-register
            bool veN = idxN >= 0;
            int  cN  = veN ? idxN : nid;
            bf16x8 hCN = *(const bf16x8*)(rec_in + (size_t)cN * RECU + 8*q);
            float4 xbN = *(const float4*)(recf + (size_t)cN * RECF + 16 + 4*q);
            float4 pn  = *(const float4*)(pos4 + (size_t)cN * 4);
            // index for tile t+2 (2-deep, off the critical chain)
            int ei2 = (t + 2) * 16 + nidx;
            idxN = (ei2 < dg) ? (int)prow[ei2] : -1;

            // current tile compute
            float dd0 = xa.x - xbC.x, dd1 = xa.y - xbC.y;
            float dd2 = xa.z - xbC.z, dd3 = xa.w - xbC.w;
            float rp = dd0*dd0 + dd1*dd1 + dd2*dd2 + dd3*dd3;  // PARTIAL radial
            float ea0 = pr.x - pc.x, ea1 = pr.y - pc.y, ea2 = pr.z - pc.z;
            unsigned k2w0 = pk2bf(rp, q0 ? ea0 : 0.0f);
            unsigned k2w1 = q0 ? pk2bf(ea1, ea2) : 0u;
            bf16x8 bK2 = bfcat(k2w0, k2w1, q0 ? 0x3F80u : 0u, 0u);

            // MLP1 remainder: col-term + K-tail on top of row-term init
            bf16x8 wc0 = *(const bf16x8*)(WB + 2048 + wb);
            bf16x8 wc1 = *(const bf16x8*)(WB + 3072 + wb);
            bf16x8 wt0 = *(const bf16x8*)(WB + 4096 + wb);
            bf16x8 wt1 = *(const bf16x8*)(WB + 5120 + wb);
            f32x4 a0 = n0, a1 = n1;
            a0 = __builtin_amdgcn_mfma_f32_16x16x32_bf16(wc0, hCC, a0, 0, 0, 0);
            a1 = __builtin_amdgcn_mfma_f32_16x16x32_bf16(wc1, hCC, a1, 0, 0, 0);
            a0 = __builtin_amdgcn_mfma_f32_16x16x32_bf16(wt0, bK2, a0, 0, 0, 0);
            a1 = __builtin_amdgcn_mfma_f32_16x16x32_bf16(wt1, bK2, a1, 0, 0, 0);

            bf16x8 bm1 = bfcat(pk2bf(silu(a0[0]), silu(a0[1])),
                               pk2bf(silu(a0[2]), silu(a0[3])),
                               pk2bf(silu(a1[0]), silu(a1[1])),
                               pk2bf(silu(a1[2]), silu(a1[3])));

            bf16x8 w20 = *(const bf16x8*)(WB + 6144 + wb);
            bf16x8 w21 = *(const bf16x8*)(WB + 7168 + wb);
            f32x4 b0 = __builtin_amdgcn_mfma_f32_16x16x32_bf16(w20, bm1, z4, 0, 0, 0);
            f32x4 b1 = __builtin_amdgcn_mfma_f32_16x16x32_bf16(w21, bm1, z4, 0, 0, 0);

            float sv0 = silu(b0[0] + eb2v0.x), sv1 = silu(b0[1] + eb2v0.y);
            float sv2 = silu(b0[2] + eb2v0.z), sv3 = silu(b0[3] + eb2v0.w);
            float sv4 = silu(b1[0] + eb2v1.x), sv5 = silu(b1[1] + eb2v1.y);
            float sv6 = silu(b1[2] + eb2v1.z), sv7 = silu(b1[3] + eb2v1.w);

            bf16x8 bm2 = bfcat(pk2bf(sv0, sv1), pk2bf(sv2, sv3),
                               pk2bf(sv4, sv5), pk2bf(sv6, sv7));

            bf16x8 cw0 = *(const bf16x8*)(WB + 8192 + wb);
            bf16x8 cw1 = *(const bf16x8*)(WB + 9216 + wb);
            f32x4 c0 = __builtin_amdgcn_mfma_f32_16x16x32_bf16(cw0, bm2, z4, 0, 0, 0);
            f32x4 c1 = __builtin_amdgcn_mfma_f32_16x16x32_bf16(cw1, bm2, z4, 0, 0, 0);
            float pp = silu(c0[0] + cb1v0.x) * cw2v0.x + silu(c0[1] + cb1v0.y) * cw2v0.y
                     + silu(c0[2] + cb1v0.z) * cw2v0.z + silu(c0[3] + cb1v0.w) * cw2v0.w
                     + silu(c1[0] + cb1v1.x) * cw2v1.x + silu(c1[1] + cb1v1.y) * cw2v1.y
                     + silu(c1[2] + cb1v1.z) * cw2v1.z + silu(c1[3] + cb1v1.w) * cw2v1.w;
            pp = sumq(pp);                  // cm at all lanes (off inter-tile path)

            if (!LAST) {                    // m-agg dead on last layer
                float msk = veC ? 1.0f : 0.0f;
                accm0 = fmaf(sv0, msk, accm0); accm1 = fmaf(sv1, msk, accm1);
                accm2 = fmaf(sv2, msk, accm2); accm3 = fmaf(sv3, msk, accm3);
                accm4 = fmaf(sv4, msk, accm4); accm5 = fmaf(sv5, msk, accm5);
                accm6 = fmaf(sv6, msk, accm6); accm7 = fmaf(sv7, msk, accm7);
            }
            // padded lanes have cC==nid -> dd==0 -> no mask needed
            accx0 += dd0 * pp; accx1 += dd1 * pp;
            accx2 += dd2 * pp; accx3 += dd3 * pp;

            veC = veN; cC = cN; hCC = hCN; xbC = xbN; pc = pn;
        }

        // DPP butterfly over the node's 16 edge lanes (pure VALU)
        accx0 = red16(accx0); accx1 = red16(accx1);
        accx2 = red16(accx2); accx3 = red16(accx3);
        if (!LAST) {
            accm0 = red16(accm0); accm1 = red16(accm1);
            accm2 = red16(accm2); accm3 = red16(accm3);
            accm4 = red16(accm4); accm5 = red16(accm5);
            accm6 = red16(accm6); accm7 = red16(accm7);
        }

        const float inv = __builtin_amdgcn_rcpf(fmaxf((float)dgf, 1.0f));
        const float xn0 = xa.x + accx0 * inv;
        const float xn1 = xa.y + accx1 * inv;
        const float xn2 = xa.z + accx2 * inv;
        const float xn3 = xa.w + accx3 * inv;

        if (!LAST) {
            if (nidx == 0) {
                *(float4*)(rec_out + (size_t)nid * RECF + 16 + 4*q) =
                    make_float4(xn0, xn1, xn2, xn3);
                *(uint2*)(maggb + (size_t)nid * H + 4*q) =
                    make_uint2(pk2bf(accm0, accm1), pk2bf(accm2, accm3));
                *(uint2*)(maggb + (size_t)nid * H + 16 + 4*q) =
                    make_uint2(pk2bf(accm4, accm5), pk2bf(accm6, accm7));
            }
        } else {   // fuse pred = lin * x_new
            float p0 = xn0*l0.x + xn1*l0.y + xn2*l0.z + xn3*l0.w;
            float p1 = xn0*l1.x + xn1*l1.y + xn2*l1.z + xn3*l1.w;
            float p2 = xn0*l2.x + xn1*l2.y + xn2*l2.z + xn3*l2.w;
            p0 = sumq(p0); p1 = sumq(p1); p2 = sumq(p2);
            if (lane == 0) {
                outp[(size_t)nid*3+0] = p0;
                outp[(size_t)nid*3+1] = p1;
                outp[(size_t)nid*3+2] = p2;
            }
        }
    }
}

// ---- MFMA node kernel: h update only; DENSE h-writes via wave-local LDS ----
__global__ __launch_bounds__(256) void node_mfma(
    const float* __restrict__ h_in, const ushort_t* __restrict__ rec_in,
    const ushort_t* __restrict__ maggb,
    const ushort_t* __restrict__ W1B, const ushort_t* __restrict__ W2B,
    const float* __restrict__ b1g, const float* __restrict__ b2g,
    ushort_t* __restrict__ rec_out, int N)
{
    __shared__ __align__(16) ushort_t Nin[64 * NPITCH];

    const int tid = threadIdx.x;
    const int n0 = blockIdx.x * 64;
    const int lane = tid & 63;
    const int w = tid >> 6;
    const int nidx = lane & 15;
    const int q = lane >> 4;

    bf16x8 w1f[2][2], w2f[2];
    #pragma unroll
    for (int kc = 0; kc < 2; ++kc)
        #pragma unroll
        for (int nt = 0; nt < 2; ++nt)
            w1f[kc][nt] = *(const bf16x8*)(W1B + (size_t)((kc*2+nt)*64 + lane) * 8);
    #pragma unroll
    for (int nt = 0; nt < 2; ++nt)
        w2f[nt] = *(const bf16x8*)(W2B + (size_t)(nt*64 + lane) * 8);
    float b1v0 = b1g[nidx], b1v1 = b1g[16+nidx];
    float b2v0 = b2g[nidx], b2v1 = b2g[16+nidx];

    {   // stage nin = [h bf16 (from record) | magg bf16] (both pre-packed)
        int e = tid >> 2, part = tid & 3;
        int n = n0 + e;
        uint4 v0 = make_uint4(0,0,0,0), v1 = v0;
        if (n < N) {
            const uint4* hp = (part < 2)
                ? (const uint4*)(rec_in + (size_t)n * RECU + part * 16)
                : (const uint4*)(maggb  + (size_t)n * H + (part - 2) * 16);
            v0 = hp[0]; v1 = hp[1];
        }
        uint4* dst = (uint4*)((char*)Nin + e * 144 + part * 32);
        dst[0] = v0; dst[1] = v1;
    }
    __syncthreads();

    const int mrow = 16 * w + nidx;
    bf16x8 a0 = *(const bf16x8*)(Nin + mrow * NPITCH + 8 * q);
    bf16x8 a1 = *(const bf16x8*)(Nin + mrow * NPITCH + 32 + 8 * q);
    f32x4 z4 = {0.0f, 0.0f, 0.0f, 0.0f};
    f32x4 acc0 = z4, acc1 = z4;
    acc0 = __builtin_amdgcn_mfma_f32_16x16x32_bf16(a0, w1f[0][0], acc0, 0, 0, 0);
    acc0 = __builtin_amdgcn_mfma_f32_16x16x32_bf16(a1, w1f[1][0], acc0, 0, 0, 0);
    acc1 = __builtin_amdgcn_mfma_f32_16x16x32_bf16(a0, w1f[0][1], acc1, 0, 0, 0);
    acc1 = __builtin_amdgcn_mfma_f32_16x16x32_bf16(a1, w1f[1][1], acc1, 0, 0, 0);

    ushort_t* u1w = Nin + w * 16 * NPITCH;   // own slab reuse (wave-ordered LDS)
    #pragma unroll
    for (int r = 0; r < 4; ++r) {
        unsigned u = pk2bf(silu(acc0[r] + b1v0), silu(acc1[r] + b1v1));
        u1w[(4*q + r) * 40 + nidx]      = (ushort_t)(u & 0xFFFFu);
        u1w[(4*q + r) * 40 + 16 + nidx] = (ushort_t)(u >> 16);
    }
    bf16x8 au = *(const bf16x8*)(u1w + nidx * 40 + 8 * q);
    f32x4 d0 = __builtin_amdgcn_mfma_f32_16x16x32_bf16(au, w2f[0], z4, 0, 0, 0);
    f32x4 d1 = __builtin_amdgcn_mfma_f32_16x16x32_bf16(au, w2f[1], z4, 0, 0, 0);
    // transpose h-out through the same slab (au consumed; same-wave ordering),
    // then write each node's 64B h-block as dense uint4s.
    #pragma unroll
    for (int r = 0; r < 4; ++r) {
        int n = n0 + 16*w + 4*q + r;
        if (n < N) {
            size_t i0 = (size_t)n * H + nidx, i1 = i0 + 16;
            u1w[(4*q + r) * 40 + nidx]      = f2bf(h_in[i0] + d0[r] + b2v0);
            u1w[(4*q + r) * 40 + 16 + nidx] = f2bf(h_in[i1] + d1[r] + b2v1);
        }
    }
    {
        int el = lane >> 2, c = lane & 3;       // 16 rows x 4 chunks = 64 lanes
        int n = n0 + 16*w + el;
        if (n < N) {
            uint4 v = *(const uint4*)((const char*)u1w + el * 80 + c * 16);
            *(uint4*)((char*)rec_out + (size_t)n * 128 + c * 16) = v;
        }
    }
}

extern "C" void kernel_launch(void* const* d_in, const int* in_sizes, int n_in,
                              void* d_out, int out_size, void* d_ws, size_t ws_size,
                              hipStream_t stream) {
    const float* node_attrs = (const float*)d_in[0];
    const float* positions  = (const float*)d_in[1];
    const int*   edge_index = (const int*)d_in[2];
    const float* proj_W   = (const float*)d_in[3];
    const float* emb_in_W = (const float*)d_in[4];
    const float* emb_in_b = (const float*)d_in[5];
    const float* edge_W1  = (const float*)d_in[6];
    const float* edge_b1  = (const float*)d_in[7];
    const float* edge_W2  = (const float*)d_in[8];
    const float* edge_b2  = (const float*)d_in[9];
    const float* node_W1  = (const float*)d_in[10];
    const float* node_b1  = (const float*)d_in[11];
    const float* node_W2  = (const float*)d_in[12];
    const float* node_b2  = (const float*)d_in[13];
    const float* coord_W1 = (const float*)d_in[14];
    const float* coord_b1 = (const float*)d_in[15];
    const float* coord_W2 = (const float*)d_in[16];
    const float* lin_W    = (const float*)d_in[19];

    const int N = in_sizes[0] / 3;
    const int E = in_sizes[2] / 2;
    const int* row = edge_index;
    const int* col = edge_index + E;

    float* rec0f = (float*)d_ws;                       // 32N f32 (128B records)
    float* rec1f = rec0f + (size_t)RECF * N;           // 32N f32
    float* h0    = rec1f + (size_t)RECF * N;           // 32N f32 (residual)
    float* pos4  = h0 + (size_t)H * N;                 // 4N f32
    ushort_t* maggb = (ushort_t*)(pos4 + (size_t)4 * N); // 32N us (bf16 m-agg)
    ushort_t* W1B  = maggb + (size_t)H * N;            // 6144
    ushort_t* W2B  = W1B + 6144;                       // 2048
    ushort_t* CW1B = W2B + 2048;                       // 2048
    ushort_t* NW1B = CW1B + 2048;                      // 4096
    ushort_t* NW2B = NW1B + 4096;                      // 2048
    int* deg    = (int*)(NW2B + 2048);                 // N
    ushort_t* pad  = (ushort_t*)(deg + N);             // N*PADC ushorts

    int eB256 = (E + 255) / 256;
    int nTiles = (N + 63) / 64;
    int ipBlocks = (8 * N + 6144 + 255) / 256;
    int rstep = (N + NSLICE - 1) / NSLICE;

    hipMemsetAsync(deg, 0, (size_t)N * sizeof(int), stream);

    // fused prologue: init blocks [0, ipBlocks) + XCD-sliced scatter after
    prologue<<<ipBlocks + eB256 * NSLICE, 256, 0, stream>>>(
        node_attrs, positions, proj_W, emb_in_W, emb_in_b,
        edge_W1, edge_b1, edge_W2, coord_W1, node_W1, node_W2,
        rec0f, (ushort_t*)rec0f, h0, pos4, deg, W1B, W2B, CW1B, NW1B, NW2B, N,
        row, col, pad, E, rstep, ipBlocks);

    // layer 0: edge (magg + x into rec1) then node h update (into rec1)
    edge_mfma<0><<<EGRID, 256, 0, stream>>>(
        pad, deg, pos4, (ushort_t*)rec0f,
        W1B, W2B, CW1B, edge_b2, coord_b1, coord_W2,
        rec1f, maggb, nullptr, nullptr, N);
    node_mfma<<<nTiles, 256, 0, stream>>>(
        h0, (ushort_t*)rec0f, maggb, NW1B, NW2B, node_b1, node_b2,
        (ushort_t*)rec1f, N);
    // layer 1: edge with fused lin projection (final h, x, magg all dead)
    edge_mfma<1><<<EGRID, 256, 0, stream>>>(
        pad, deg, pos4, (ushort_t*)rec1f,
        W1B + 3072, W2B + 1024, CW1B + 1024,
        edge_b2 + H, coord_b1 + H, coord_W2 + H,
        nullptr, nullptr, lin_W, (float*)d_out, N);
}